// Round 1
// baseline (1545.165 us; speedup 1.0000x reference)
//
#include <hip/hip_runtime.h>
#include <math.h>

// Problem constants: B=16, C_IN=256, C_OUT=256, H=W=64, K=3, NK=2
// weights layout: [2][256][256][3][3]; bank stride = 256*256*9 = 589824 floats
// per-(o) stride = 256*9 = 2304 floats

// ---------------------------------------------------------------------------
// Kernel 1: per-(b,o) demodulation scale = rsqrt(max(sum_{i,k,l} w'^2, 1e-8))
// where w' = (a0*W0 + a1*W1) * (mod[b,i]+1)
// ---------------------------------------------------------------------------
__global__ __launch_bounds__(256) void scale_kernel(
    const float* __restrict__ mod, const float* __restrict__ kmod,
    const float* __restrict__ weights, float* __restrict__ scale) {
  int bo = blockIdx.x;
  int b = bo >> 8, o = bo & 255;

  float k0 = kmod[b * 2 + 0], k1 = kmod[b * 2 + 1];
  float mx = fmaxf(k0, k1);
  float e0 = expf(k0 - mx), e1 = expf(k1 - mx);
  float ai = 1.0f / (e0 + e1);
  float a0 = e0 * ai, a1 = e1 * ai;

  int t = threadIdx.x;
  const float* w0 = weights + (size_t)o * 2304;
  const float* w1 = weights + (size_t)589824 + (size_t)o * 2304;

  float s = 0.0f;
#pragma unroll
  for (int r = 0; r < 9; r++) {
    int idx = t + r * 256;     // 0..2303, coalesced over weights
    int i = idx / 9;
    float wv = a0 * w0[idx] + a1 * w1[idx];
    wv *= (mod[b * 256 + i] + 1.0f);
    s += wv * wv;
  }
#pragma unroll
  for (int off = 32; off > 0; off >>= 1) s += __shfl_down(s, off);

  __shared__ float red[4];
  if ((t & 63) == 0) red[t >> 6] = s;
  __syncthreads();
  if (t == 0) {
    float tot = red[0] + red[1] + red[2] + red[3];
    scale[bo] = rsqrtf(fmaxf(tot, 1e-8f));
  }
}

// ---------------------------------------------------------------------------
// Kernel 2: direct conv, per-sample weights combined on the fly.
// Block tile: 64 output channels x 2 rows x 64 pixels. 256 threads:
//   p = t&63 (pixel), og = t>>6 (o-subgroup of 16). acc[2 rows][16 o].
// C_IN looped in chunks of 8, x + combined weights staged in LDS.
// ---------------------------------------------------------------------------
__global__ __launch_bounds__(256) void conv_kernel(
    const float* __restrict__ x, const float* __restrict__ mod,
    const float* __restrict__ kmod, const float* __restrict__ weights,
    const float* __restrict__ scale, float* __restrict__ out) {
  __shared__ __align__(16) float xs[8][4][66];   // [ii][row h0-1..h0+2][col -1..64]
  __shared__ __align__(16) float wsh[8][9][68];  // [ii][j][o_local], pad 68 -> 16B-aligned rows

  int blk = blockIdx.x;
  int b = blk >> 7;
  int ot = (blk >> 5) & 3;
  int h0 = (blk & 31) * 2;

  int t = threadIdx.x;
  int p = t & 63, og = t >> 6;

  float k0 = kmod[b * 2 + 0], k1 = kmod[b * 2 + 1];
  float mx = fmaxf(k0, k1);
  float e0 = expf(k0 - mx), e1 = expf(k1 - mx);
  float ai = 1.0f / (e0 + e1);
  float a0 = e0 * ai, a1 = e1 * ai;

  float acc[2][16];
#pragma unroll
  for (int r = 0; r < 2; r++)
#pragma unroll
    for (int oo = 0; oo < 16; oo++) acc[r][oo] = 0.0f;

  for (int ic0 = 0; ic0 < 256; ic0 += 8) {
    __syncthreads();
    // ---- stage x tile: 8 ci x 4 rows x 66 cols (zero-padded halo) ----
    for (int idx = t; idx < 2112; idx += 256) {
      int ii = idx / 264;
      int rem = idx - ii * 264;
      int dh = rem / 66;
      int c = rem - dh * 66;
      int row = h0 - 1 + dh;
      int col = c - 1;
      float v = 0.0f;
      if (row >= 0 && row < 64 && col >= 0 && col < 64)
        v = x[(((size_t)b * 256 + ic0 + ii) * 64 + row) * 64 + col];
      xs[ii][dh][c] = v;
    }
    // ---- stage combined weights: 8 ci x 9 taps x 64 o ----
#pragma unroll
    for (int r = 0; r < 18; r++) {
      int idx = t + r * 256;       // 0..4607
      int ol = idx / 72;
      int q = idx - ol * 72;       // q = ii*9 + j -> coalesced global reads
      int ii = q / 9;
      int j = q - ii * 9;
      int o = ot * 64 + ol;
      size_t gi = ((size_t)o * 256 + ic0 + ii) * 9 + j;
      float wv = a0 * weights[gi] + a1 * weights[589824 + gi];
      wv *= (mod[b * 256 + ic0 + ii] + 1.0f) * scale[b * 256 + o];
      wsh[ii][j][ol] = wv;
    }
    __syncthreads();
    // ---- compute ----
#pragma unroll
    for (int ii = 0; ii < 8; ii++) {
      float xv[4][3];
#pragma unroll
      for (int dh = 0; dh < 4; dh++)
#pragma unroll
        for (int c = 0; c < 3; c++) xv[dh][c] = xs[ii][dh][p + c];
#pragma unroll
      for (int j = 0; j < 9; j++) {
        int kh = j / 3, kw = j - kh * 3;
        float x0 = xv[kh][kw];
        float x1 = xv[kh + 1][kw];
        const float4* wp = (const float4*)&wsh[ii][j][og * 16];
#pragma unroll
        for (int v4 = 0; v4 < 4; v4++) {
          float4 wv = wp[v4];
          int ob = v4 * 4;
          acc[0][ob + 0] = fmaf(wv.x, x0, acc[0][ob + 0]);
          acc[0][ob + 1] = fmaf(wv.y, x0, acc[0][ob + 1]);
          acc[0][ob + 2] = fmaf(wv.z, x0, acc[0][ob + 2]);
          acc[0][ob + 3] = fmaf(wv.w, x0, acc[0][ob + 3]);
          acc[1][ob + 0] = fmaf(wv.x, x1, acc[1][ob + 0]);
          acc[1][ob + 1] = fmaf(wv.y, x1, acc[1][ob + 1]);
          acc[1][ob + 2] = fmaf(wv.z, x1, acc[1][ob + 2]);
          acc[1][ob + 3] = fmaf(wv.w, x1, acc[1][ob + 3]);
        }
      }
    }
  }
  // ---- write (coalesced: lane = pixel) ----
#pragma unroll
  for (int r = 0; r < 2; r++)
#pragma unroll
    for (int oo = 0; oo < 16; oo++) {
      int o = ot * 64 + og * 16 + oo;
      out[(((size_t)b * 256 + o) * 64 + (h0 + r)) * 64 + p] = acc[r][oo];
    }
}

// ---------------------------------------------------------------------------
// Kernel 3: channel RMS norm (F.normalize over dim=1) * gamma * 16 + SiLU,
// in place on d_out. One block per (b,h) row; values kept in registers.
// ---------------------------------------------------------------------------
__global__ __launch_bounds__(256) void norm_kernel(
    float* __restrict__ y, const float* __restrict__ gamma) {
  int blk = blockIdx.x;
  int b = blk >> 6, h = blk & 63;
  int t = threadIdx.x;
  int p = t & 63, og = t >> 6;

  size_t base = (((size_t)b * 256) * 64 + h) * 64 + p;
  float yv[64];
  float s = 0.0f;
#pragma unroll
  for (int k = 0; k < 64; k++) {
    yv[k] = y[base + (size_t)(og * 64 + k) * 4096];
    s = fmaf(yv[k], yv[k], s);
  }

  __shared__ float red[4][64];
  __shared__ float invs[64];
  red[og][p] = s;
  __syncthreads();
  if (og == 0) {
    float tot = red[0][p] + red[1][p] + red[2][p] + red[3][p];
    float nrm = sqrtf(tot);
    invs[p] = 16.0f / fmaxf(nrm, 1e-12f);
  }
  __syncthreads();
  float iv = invs[p];
#pragma unroll
  for (int k = 0; k < 64; k++) {
    int o = og * 64 + k;
    float v = yv[k] * iv * gamma[o];
    float sg = 1.0f / (1.0f + expf(-v));
    y[base + (size_t)o * 4096] = v * sg;
  }
}

extern "C" void kernel_launch(void* const* d_in, const int* in_sizes, int n_in,
                              void* d_out, int out_size, void* d_ws, size_t ws_size,
                              hipStream_t stream) {
  const float* x = (const float*)d_in[0];
  const float* mod = (const float*)d_in[1];
  const float* kmod = (const float*)d_in[2];
  const float* weights = (const float*)d_in[3];
  const float* gamma = (const float*)d_in[4];
  float* out = (float*)d_out;
  float* scale = (float*)d_ws;  // 16*256 floats = 16 KB

  scale_kernel<<<16 * 256, 256, 0, stream>>>(mod, kmod, weights, scale);
  conv_kernel<<<16 * 4 * 32, 256, 0, stream>>>(x, mod, kmod, weights, scale, out);
  norm_kernel<<<16 * 64, 256, 0, stream>>>(out, gamma);
}

// Round 2
// 197.514 us; speedup vs baseline: 7.8231x; 7.8231x over previous
//
#include <hip/hip_runtime.h>
#include <math.h>

// B=16, C_IN=256, C_OUT=256, H=W=64, K=3, NK=2
// weights: [2][256][256][3][3]; bank stride 589824 floats; per-o stride 2304.
//
// Pipeline:
//  1. scale_kernel: per (b,o) demod scale -> ws[scale]
//  2. wprep: combined+modulated+demod weights -> bf16 in ws[wq], laid out in the
//     exact LDS image the conv kernel stages: per (b,ot,c16): [p=20][ol=128][e=8]
//     where p = io_loc*10 + j (j=9 is a zero "dummy tap" making 10 taps), i = c*16+io_loc*8+e.
//  3. conv_mfma: implicit GEMM, mfma_f32_16x16x32_bf16. Block = 128 o x 256 px
//     (4 rows x 64 cols), 4 waves (wave = one out row, tile 128x64).
//     K enumerated as (i-oct, tap) pairs; lane-group g of each MFMA takes pair 4s+g.
//  4. norm_kernel: channel RMSNorm * gamma * 16 + SiLU in place.

typedef __attribute__((ext_vector_type(8))) short short8;
typedef __attribute__((ext_vector_type(4))) float f32x4;

static __device__ __forceinline__ unsigned short f2bf(float v) {
  union { float f; unsigned u; } u;
  u.f = v;
  unsigned r = u.u + 0x7FFF + ((u.u >> 16) & 1);  // RNE
  return (unsigned short)(r >> 16);
}

// ---------------------------------------------------------------------------
// Kernel 1: per-(b,o) demodulation scale
// ---------------------------------------------------------------------------
__global__ __launch_bounds__(256) void scale_kernel(
    const float* __restrict__ mod, const float* __restrict__ kmod,
    const float* __restrict__ weights, float* __restrict__ scale) {
  int bo = blockIdx.x;
  int b = bo >> 8, o = bo & 255;

  float k0 = kmod[b * 2 + 0], k1 = kmod[b * 2 + 1];
  float mx = fmaxf(k0, k1);
  float e0 = expf(k0 - mx), e1 = expf(k1 - mx);
  float ai = 1.0f / (e0 + e1);
  float a0 = e0 * ai, a1 = e1 * ai;

  int t = threadIdx.x;
  const float* w0 = weights + (size_t)o * 2304;
  const float* w1 = w0 + 589824;

  float s = 0.0f;
#pragma unroll
  for (int r = 0; r < 9; r++) {
    int idx = t + r * 256;
    int i = idx / 9;
    float wv = a0 * w0[idx] + a1 * w1[idx];
    wv *= (mod[b * 256 + i] + 1.0f);
    s += wv * wv;
  }
#pragma unroll
  for (int off = 32; off > 0; off >>= 1) s += __shfl_down(s, off);

  __shared__ float red[4];
  if ((t & 63) == 0) red[t >> 6] = s;
  __syncthreads();
  if (t == 0) {
    float tot = red[0] + red[1] + red[2] + red[3];
    scale[bo] = rsqrtf(fmaxf(tot, 1e-8f));
  }
}

// ---------------------------------------------------------------------------
// Kernel 2: weight prep -> bf16 LDS-image in ws. Block = (b, ot, c): 512 blocks.
// Writes 20480 ushort = 40960 B contiguous per block.
// ---------------------------------------------------------------------------
__global__ __launch_bounds__(256) void wprep(
    const float* __restrict__ mod, const float* __restrict__ kmod,
    const float* __restrict__ weights, const float* __restrict__ scale,
    unsigned short* __restrict__ wq) {
  __shared__ __align__(16) unsigned short buf[20480];
  int blk = blockIdx.x;                 // b*32 + ot*16 + c
  int b = blk >> 5, ot = (blk >> 4) & 1, c = blk & 15;
  int t = threadIdx.x;

  float k0 = kmod[b * 2 + 0], k1 = kmod[b * 2 + 1];
  float mx = fmaxf(k0, k1);
  float e0 = expf(k0 - mx), e1 = expf(k1 - mx);
  float ai = 1.0f / (e0 + e1);
  float a0 = e0 * ai, a1 = e1 * ai;

  // zero the two dummy-tap rows (p=9, p=19): 2048 elems
#pragma unroll
  for (int k = 0; k < 8; ++k) {
    int e = t + k * 256;
    int half = e >> 10;
    buf[(half * 10 + 9) * 1024 + (e & 1023)] = 0;
  }

  int ol = t >> 1, eh = t & 1;
  int o = ot * 128 + ol;
  float sc = scale[b * 256 + o];
#pragma unroll
  for (int io = 0; io < 2; ++io) {
#pragma unroll
    for (int eo = 0; eo < 4; ++eo) {
      int e = eh * 4 + eo;
      int i = c * 16 + io * 8 + e;
      float f = (mod[b * 256 + i] + 1.0f) * sc;
      const float* w0 = &weights[((size_t)o * 256 + i) * 9];
      const float* w1 = w0 + 589824;
#pragma unroll
      for (int j = 0; j < 9; ++j) {
        float v = (a0 * w0[j] + a1 * w1[j]) * f;
        buf[(io * 10 + j) * 1024 + ol * 8 + e] = f2bf(v);
      }
    }
  }
  __syncthreads();
  size_t base = (size_t)blk * 20480;
#pragma unroll
  for (int k = 0; k < 10; ++k) {
    int idx = t + k * 256;  // 0..2559 short8 groups
    *(short8*)(wq + base + (size_t)idx * 8) = *(const short8*)&buf[idx * 8];
  }
}

// ---------------------------------------------------------------------------
// Kernel 3: implicit-GEMM conv via bf16 MFMA.
// Grid 512 = 16 b x 2 ot x 16 row-tiles (XCD-swizzled). Block 256 thr (4 waves).
// ---------------------------------------------------------------------------
__global__ __launch_bounds__(256, 2) void conv_mfma(
    const float* __restrict__ x, const unsigned short* __restrict__ wq,
    float* __restrict__ out) {
  // xs: [dh 7][colp 66][i 24pad] bf16 (row 6 only touched by dummy-tap reads)
  __shared__ __align__(16) unsigned short xsm[7 * 66 * 24];   // 22176 B
  __shared__ __align__(16) unsigned short wsm[20 * 128 * 8];  // 40960 B

  int bid = blockIdx.x;
  int lg = (bid & 7) * 64 + (bid >> 3);  // XCD swizzle: 64 consecutive logical blocks per XCD
  int grp = lg >> 4;                     // (b,ot) 0..31
  int rt = lg & 15;
  int b = grp >> 1, ot = grp & 1;
  int r0 = rt * 4;

  int t = threadIdx.x;
  int w = t >> 6;        // wave id = out row in tile
  int lane = t & 63;
  int g = (t >> 4) & 3;  // MFMA lane-group
  int lm = t & 15;

  f32x4 acc[8][4];
#pragma unroll
  for (int mf = 0; mf < 8; ++mf)
#pragma unroll
    for (int nf = 0; nf < 4; ++nf) acc[mf][nf] = (f32x4){0.f, 0.f, 0.f, 0.f};

  const size_t wqbase = (size_t)grp * 16 * 20480;

  for (int c = 0; c < 16; ++c) {
    __syncthreads();
    int ic0 = c * 16;
    // ---- stage x: 16 i x 6 rows x 66 cols, transposed to i-innermost ----
#pragma unroll
    for (int k = 0; k < 25; ++k) {
      int idx = t + k * 256;
      if (idx < 6336) {
        int colp = idx % 66;
        int tmp = idx / 66;
        int dh = tmp % 6;
        int il = tmp / 6;
        int row = r0 + dh - 1;
        int col = colp - 1;
        float v = 0.f;
        if ((unsigned)row < 64u && (unsigned)col < 64u)
          v = x[(((size_t)b * 256 + ic0 + il) * 64 + row) * 64 + col];
        xsm[(dh * 66 + colp) * 24 + il] = f2bf(v);
      }
    }
    // ---- stage weights: linear 40960 B via global_load_lds width-16 ----
    {
      const unsigned short* src = wq + wqbase + (size_t)c * 20480 + w * 5120 + lane * 8;
      unsigned short* dst = &wsm[w * 5120];  // wave-uniform base
#pragma unroll
      for (int it = 0; it < 10; ++it) {
        __builtin_amdgcn_global_load_lds(
            (const __attribute__((address_space(1))) unsigned int*)(src + it * 512),
            (__attribute__((address_space(3))) unsigned int*)(dst + it * 512),
            16, 0, 0);
      }
    }
    __syncthreads();

    const char* wsb = (const char*)wsm;
    const char* xsb = (const char*)xsm;
#pragma unroll
    for (int s = 0; s < 5; ++s) {
      int p = 4 * s + g;
      int io = (p >= 10) ? 1 : 0;
      int j = p - 10 * io;                       // 0..9 (9 = dummy, zero weights)
      int jd3 = (j >= 3) + (j >= 6) + (j >= 9);  // kh (3 for dummy -> row 6, in-bounds)
      int jm3 = j - 3 * jd3;                     // kw
      int baddr = ((w + jd3) * 66 + lm + jm3) * 48 + io * 16;
      int aaddr = p * 2048 + lm * 16;
      short8 A[8];
#pragma unroll
      for (int mf = 0; mf < 8; ++mf)
        A[mf] = *(const short8*)(wsb + aaddr + mf * 256);
#pragma unroll
      for (int nf = 0; nf < 4; ++nf) {
        short8 B = *(const short8*)(xsb + baddr + nf * 768);
#pragma unroll
        for (int mf = 0; mf < 8; ++mf)
          acc[mf][nf] = __builtin_amdgcn_mfma_f32_16x16x32_bf16(A[mf], B, acc[mf][nf], 0, 0, 0);
      }
    }
  }
  // ---- epilogue: D col=lane&15 (px), row=4*(lane>>4)+q (o) ----
  int row = r0 + w;
#pragma unroll
  for (int mf = 0; mf < 8; ++mf)
#pragma unroll
    for (int nf = 0; nf < 4; ++nf)
#pragma unroll
      for (int q = 0; q < 4; ++q) {
        int o = ot * 128 + mf * 16 + g * 4 + q;
        int col = nf * 16 + lm;
        out[(((size_t)b * 256 + o) * 64 + row) * 64 + col] = acc[mf][nf][q];
      }
}

// ---------------------------------------------------------------------------
// Kernel 4: channel RMSNorm * gamma * 16 + SiLU, in place.
// ---------------------------------------------------------------------------
__global__ __launch_bounds__(256) void norm_kernel(
    float* __restrict__ y, const float* __restrict__ gamma) {
  int blk = blockIdx.x;
  int b = blk >> 6, h = blk & 63;
  int t = threadIdx.x;
  int p = t & 63, og = t >> 6;

  size_t base = (((size_t)b * 256) * 64 + h) * 64 + p;
  float yv[64];
  float s = 0.0f;
#pragma unroll
  for (int k = 0; k < 64; k++) {
    yv[k] = y[base + (size_t)(og * 64 + k) * 4096];
    s = fmaf(yv[k], yv[k], s);
  }

  __shared__ float red[4][64];
  __shared__ float invs[64];
  red[og][p] = s;
  __syncthreads();
  if (og == 0) {
    float tot = red[0][p] + red[1][p] + red[2][p] + red[3][p];
    float nrm = sqrtf(tot);
    invs[p] = 16.0f / fmaxf(nrm, 1e-12f);
  }
  __syncthreads();
  float iv = invs[p];
#pragma unroll
  for (int k = 0; k < 64; k++) {
    int o = og * 64 + k;
    float v = yv[k] * iv * gamma[o];
    float sg = 1.0f / (1.0f + expf(-v));
    y[base + (size_t)o * 4096] = v * sg;
  }
}

extern "C" void kernel_launch(void* const* d_in, const int* in_sizes, int n_in,
                              void* d_out, int out_size, void* d_ws, size_t ws_size,
                              hipStream_t stream) {
  const float* x = (const float*)d_in[0];
  const float* mod = (const float*)d_in[1];
  const float* kmod = (const float*)d_in[2];
  const float* weights = (const float*)d_in[3];
  const float* gamma = (const float*)d_in[4];
  float* out = (float*)d_out;

  unsigned short* wq = (unsigned short*)d_ws;                  // 20,971,520 B
  float* scale = (float*)((char*)d_ws + 20971520);             // 16 KB

  scale_kernel<<<16 * 256, 256, 0, stream>>>(mod, kmod, weights, scale);
  wprep<<<512, 256, 0, stream>>>(mod, kmod, weights, scale, wq);
  conv_mfma<<<512, 256, 0, stream>>>(x, wq, out);
  norm_kernel<<<16 * 64, 256, 0, stream>>>(out, gamma);
}

// Round 3
// 143.023 us; speedup vs baseline: 10.8036x; 1.3810x over previous
//
#include <hip/hip_runtime.h>
#include <math.h>

// B=16, C_IN=256, C_OUT=256, H=W=64, K=3, NK=2
// weights: [2][256][256][3][3]; bank stride 589824 floats; per-o stride 2304.
//
// Pipeline:
//  1. scale_kernel: per (b,o) demod scale -> ws[scale]
//  2. wprep: combined+modulated+demod weights -> bf16 wq, LDS-image layout
//     per (b,ot,c16): [p=20][ol=128][e=8], p = io*10 + j (j=9 zero dummy tap).
//  3. xprep: x -> bf16 xq [b][c16][rowp 66][colp 66][i 16], halo zeros baked.
//  4. conv_mfma: implicit GEMM via mfma_f32_16x16x32_bf16, 2-phase
//     double-buffered pipeline. Block = 512 thr (8 waves) = 128 o x 8 rows x 64 px.
//     Grid 256 (1 block/CU). K enumerated as (i-oct, tap) pairs; lane-group g
//     of each MFMA takes pair 4s+g.
//  5. norm_kernel: channel RMSNorm * gamma * 16 + SiLU in place.

typedef __attribute__((ext_vector_type(8))) short short8;
typedef __attribute__((ext_vector_type(4))) float f32x4;

#define GLL16(src, dst)                                                       \
  __builtin_amdgcn_global_load_lds(                                           \
      (const __attribute__((address_space(1))) unsigned int*)(src),           \
      (__attribute__((address_space(3))) unsigned int*)(dst), 16, 0, 0)

static __device__ __forceinline__ unsigned short f2bf(float v) {
  union { float f; unsigned u; } u;
  u.f = v;
  unsigned r = u.u + 0x7FFF + ((u.u >> 16) & 1);  // RNE
  return (unsigned short)(r >> 16);
}

// ---------------------------------------------------------------------------
// Kernel 1: per-(b,o) demodulation scale
// ---------------------------------------------------------------------------
__global__ __launch_bounds__(256) void scale_kernel(
    const float* __restrict__ mod, const float* __restrict__ kmod,
    const float* __restrict__ weights, float* __restrict__ scale) {
  int bo = blockIdx.x;
  int b = bo >> 8, o = bo & 255;

  float k0 = kmod[b * 2 + 0], k1 = kmod[b * 2 + 1];
  float mx = fmaxf(k0, k1);
  float e0 = expf(k0 - mx), e1 = expf(k1 - mx);
  float ai = 1.0f / (e0 + e1);
  float a0 = e0 * ai, a1 = e1 * ai;

  int t = threadIdx.x;
  const float* w0 = weights + (size_t)o * 2304;
  const float* w1 = w0 + 589824;

  float s = 0.0f;
#pragma unroll
  for (int r = 0; r < 9; r++) {
    int idx = t + r * 256;
    int i = idx / 9;
    float wv = a0 * w0[idx] + a1 * w1[idx];
    wv *= (mod[b * 256 + i] + 1.0f);
    s += wv * wv;
  }
#pragma unroll
  for (int off = 32; off > 0; off >>= 1) s += __shfl_down(s, off);

  __shared__ float red[4];
  if ((t & 63) == 0) red[t >> 6] = s;
  __syncthreads();
  if (t == 0) {
    float tot = red[0] + red[1] + red[2] + red[3];
    scale[bo] = rsqrtf(fmaxf(tot, 1e-8f));
  }
}

// ---------------------------------------------------------------------------
// Kernel 2: weight prep -> bf16 LDS-image in wq. Block = (b, ot, c): 512 blocks.
// ---------------------------------------------------------------------------
__global__ __launch_bounds__(256) void wprep(
    const float* __restrict__ mod, const float* __restrict__ kmod,
    const float* __restrict__ weights, const float* __restrict__ scale,
    unsigned short* __restrict__ wq) {
  __shared__ __align__(16) unsigned short buf[20480];
  int blk = blockIdx.x;                 // b*32 + ot*16 + c
  int b = blk >> 5, ot = (blk >> 4) & 1, c = blk & 15;
  int t = threadIdx.x;

  float k0 = kmod[b * 2 + 0], k1 = kmod[b * 2 + 1];
  float mx = fmaxf(k0, k1);
  float e0 = expf(k0 - mx), e1 = expf(k1 - mx);
  float ai = 1.0f / (e0 + e1);
  float a0 = e0 * ai, a1 = e1 * ai;

  // zero the two dummy-tap rows (p=9, p=19)
#pragma unroll
  for (int k = 0; k < 8; ++k) {
    int e = t + k * 256;
    int half = e >> 10;
    buf[(half * 10 + 9) * 1024 + (e & 1023)] = 0;
  }

  int ol = t >> 1, eh = t & 1;
  int o = ot * 128 + ol;
  float sc = scale[b * 256 + o];
#pragma unroll
  for (int io = 0; io < 2; ++io) {
#pragma unroll
    for (int eo = 0; eo < 4; ++eo) {
      int e = eh * 4 + eo;
      int i = c * 16 + io * 8 + e;
      float f = (mod[b * 256 + i] + 1.0f) * sc;
      const float* w0 = &weights[((size_t)o * 256 + i) * 9];
      const float* w1 = w0 + 589824;
#pragma unroll
      for (int j = 0; j < 9; ++j) {
        float v = (a0 * w0[j] + a1 * w1[j]) * f;
        buf[(io * 10 + j) * 1024 + ol * 8 + e] = f2bf(v);
      }
    }
  }
  __syncthreads();
  size_t base = (size_t)blk * 20480;
#pragma unroll
  for (int k = 0; k < 10; ++k) {
    int idx = t + k * 256;
    *(short8*)(wq + base + (size_t)idx * 8) = *(const short8*)&buf[idx * 8];
  }
}

// ---------------------------------------------------------------------------
// Kernel 3: x prep -> bf16 xq [b][c16][rowp 66][colp 66][i 16], halo zeroed.
// Grid = 16*16*66 blocks; block handles one (b,c,rowp).
// ---------------------------------------------------------------------------
__global__ __launch_bounds__(256) void xprep(
    const float* __restrict__ x, unsigned short* __restrict__ xq) {
  int blk = blockIdx.x;            // (b*16 + c)*66 + rowp
  int rowp = blk % 66;
  int bc = blk / 66;
  int b = bc >> 4, c = bc & 15;
  int t = threadIdx.x;
  size_t obase = (size_t)blk * 1056;

  if (rowp == 0 || rowp == 65) {
    for (int idx = t; idx < 1056; idx += 256) xq[obase + idx] = 0;
    return;
  }
  __shared__ __align__(16) unsigned short xs2[1056];
  int row = rowp - 1;
  for (int idx = t; idx < 1056; idx += 256) xs2[idx] = 0;
  __syncthreads();
#pragma unroll
  for (int k = 0; k < 4; ++k) {
    int idx = t + k * 256;  // 0..1023
    int il = idx >> 6, col = idx & 63;
    float v = x[(((size_t)b * 256 + c * 16 + il) * 64 + row) * 64 + col];
    xs2[(col + 1) * 16 + il] = f2bf(v);
  }
  __syncthreads();
  if (t < 132) *(short8*)(xq + obase + (size_t)t * 8) = *(const short8*)&xs2[t * 8];
}

// ---------------------------------------------------------------------------
// Kernel 4: implicit-GEMM conv, 2-phase double-buffered.
// Grid 256 = 16 b x 2 ot x 8 row-tiles. Block 512 thr (8 waves), wave = row.
// ---------------------------------------------------------------------------
__global__ __launch_bounds__(512, 2) void conv_mfma(
    const unsigned short* __restrict__ xq, const unsigned short* __restrict__ wq,
    float* __restrict__ out) {
  __shared__ __align__(16) unsigned short wsm[2][20480];  // [p20][ol128][e8]
  __shared__ __align__(16) unsigned short xsm[2][15840];  // [rl10][colp66][i24]

  int bid = blockIdx.x;
  int b = bid >> 4, ot = (bid >> 3) & 1, rt = bid & 7;
  int grp = b * 2 + ot;
  int r0 = rt * 8;

  int t = threadIdx.x;
  int w = t >> 6, lane = t & 63;
  int g = (t >> 4) & 3, lm = t & 15;

  // per-s LDS read offsets (loop-invariant across c)
  int baddr_[5], aaddr_[5];
#pragma unroll
  for (int s = 0; s < 5; ++s) {
    int p = 4 * s + g;
    int io = (p >= 10) ? 1 : 0;
    int j = p - 10 * io;
    int jd3, jm3;
    if (j == 9) { jd3 = 0; jm3 = 0; }       // dummy tap: weights zero, any staged value
    else { jd3 = (j >= 3) + (j >= 6); jm3 = j - 3 * jd3; }
    baddr_[s] = ((w + jd3) * 66 + lm + jm3) * 48 + io * 16;
    aaddr_[s] = p * 2048 + lm * 16;
  }

  // x-stage LDS offsets (elements), invariant across c
  int xo0, xo1, xo2;
  {
    int i0 = t, i1 = t + 512, i2 = t + 1024;
    int rl, rem;
    rl = i0 / 132; rem = i0 - rl * 132; xo0 = (rl * 66 + (rem >> 1)) * 24 + (rem & 1) * 8;
    rl = i1 / 132; rem = i1 - rl * 132; xo1 = (rl * 66 + (rem >> 1)) * 24 + (rem & 1) * 8;
    rl = i2 / 132; rem = i2 - rl * 132; xo2 = (rl * 66 + (rem >> 1)) * 24 + (rem & 1) * 8;
  }

  f32x4 acc[8][4];
#pragma unroll
  for (int mf = 0; mf < 8; ++mf)
#pragma unroll
    for (int nf = 0; nf < 4; ++nf) acc[mf][nf] = (f32x4){0.f, 0.f, 0.f, 0.f};

  short8 xr0, xr1, xr2;

#define XLOAD(cn)                                                              \
  {                                                                            \
    const unsigned short* xs_ = xq + (size_t)(((b * 16 + (cn)) * 66 + r0)) * 1056; \
    xr0 = *(const short8*)(xs_ + (size_t)t * 8);                               \
    xr1 = *(const short8*)(xs_ + (size_t)(t + 512) * 8);                       \
    if (t < 296) xr2 = *(const short8*)(xs_ + (size_t)(t + 1024) * 8);         \
  }

#define WSTAGE(cn, nb)                                                         \
  {                                                                            \
    const unsigned short* ws_ =                                                \
        wq + ((size_t)grp * 16 + (cn)) * 20480 + (w * 5) * 512 + lane * 8;     \
    unsigned short* wd_ = &wsm[nb][(w * 5) * 512];                             \
    _Pragma("unroll")                                                          \
    for (int it = 0; it < 5; ++it) GLL16(ws_ + it * 512, wd_ + it * 512);      \
  }

#define XWRITE(nb)                                                             \
  {                                                                            \
    *(short8*)&xsm[nb][xo0] = xr0;                                             \
    *(short8*)&xsm[nb][xo1] = xr1;                                             \
    if (t < 296) *(short8*)&xsm[nb][xo2] = xr2;                                \
  }

  // prologue: stage c=0 into buffer 0
  XLOAD(0);
  WSTAGE(0, 0);
  XWRITE(0);
  __syncthreads();

  for (int c = 0; c < 16; ++c) {
    int cur = c & 1;
    if (c < 15) {
      XLOAD(c + 1);
      WSTAGE(c + 1, cur ^ 1);
    }
    // ---- compute on buffer cur ----
    {
      const char* wsb = (const char*)wsm[cur];
      const char* xsb = (const char*)xsm[cur];
#pragma unroll
      for (int s = 0; s < 5; ++s) {
        short8 A[8];
#pragma unroll
        for (int mf = 0; mf < 8; ++mf)
          A[mf] = *(const short8*)(wsb + aaddr_[s] + mf * 256);
#pragma unroll
        for (int nf = 0; nf < 4; ++nf) {
          short8 Bf = *(const short8*)(xsb + baddr_[s] + nf * 768);
#pragma unroll
          for (int mf = 0; mf < 8; ++mf)
            acc[mf][nf] =
                __builtin_amdgcn_mfma_f32_16x16x32_bf16(A[mf], Bf, acc[mf][nf], 0, 0, 0);
        }
      }
    }
    if (c < 15) XWRITE(cur ^ 1);
    __syncthreads();
  }

  // ---- epilogue: D col=lane&15 (px), row-in-frag=4*(lane>>4)+q (o) ----
  int row = r0 + w;
#pragma unroll
  for (int mf = 0; mf < 8; ++mf)
#pragma unroll
    for (int nf = 0; nf < 4; ++nf)
#pragma unroll
      for (int q = 0; q < 4; ++q) {
        int o = ot * 128 + mf * 16 + g * 4 + q;
        int col = nf * 16 + lm;
        out[(((size_t)b * 256 + o) * 64 + row) * 64 + col] = acc[mf][nf][q];
      }
#undef XLOAD
#undef WSTAGE
#undef XWRITE
}

// ---------------------------------------------------------------------------
// Kernel 5: channel RMSNorm * gamma * 16 + SiLU, in place.
// ---------------------------------------------------------------------------
__global__ __launch_bounds__(256) void norm_kernel(
    float* __restrict__ y, const float* __restrict__ gamma) {
  int blk = blockIdx.x;
  int b = blk >> 6, h = blk & 63;
  int t = threadIdx.x;
  int p = t & 63, og = t >> 6;

  size_t base = (((size_t)b * 256) * 64 + h) * 64 + p;
  float yv[64];
  float s = 0.0f;
#pragma unroll
  for (int k = 0; k < 64; k++) {
    yv[k] = y[base + (size_t)(og * 64 + k) * 4096];
    s = fmaf(yv[k], yv[k], s);
  }

  __shared__ float red[4][64];
  __shared__ float invs[64];
  red[og][p] = s;
  __syncthreads();
  if (og == 0) {
    float tot = red[0][p] + red[1][p] + red[2][p] + red[3][p];
    float nrm = sqrtf(tot);
    invs[p] = 16.0f / fmaxf(nrm, 1e-12f);
  }
  __syncthreads();
  float iv = invs[p];
#pragma unroll
  for (int k = 0; k < 64; k++) {
    int o = og * 64 + k;
    float v = yv[k] * iv * gamma[o];
    float sg = 1.0f / (1.0f + expf(-v));
    y[base + (size_t)o * 4096] = v * sg;
  }
}

extern "C" void kernel_launch(void* const* d_in, const int* in_sizes, int n_in,
                              void* d_out, int out_size, void* d_ws, size_t ws_size,
                              hipStream_t stream) {
  const float* x = (const float*)d_in[0];
  const float* mod = (const float*)d_in[1];
  const float* kmod = (const float*)d_in[2];
  const float* weights = (const float*)d_in[3];
  const float* gamma = (const float*)d_in[4];
  float* out = (float*)d_out;

  // ws layout: wq 20,971,520 B | scale 16,384 B | xq 35,684,352 B  (~56.7 MB)
  unsigned short* wq = (unsigned short*)d_ws;
  float* scale = (float*)((char*)d_ws + 20971520);
  unsigned short* xq = (unsigned short*)((char*)d_ws + 20987904);

  scale_kernel<<<16 * 256, 256, 0, stream>>>(mod, kmod, weights, scale);
  wprep<<<512, 256, 0, stream>>>(mod, kmod, weights, scale, wq);
  xprep<<<16 * 16 * 66, 256, 0, stream>>>(x, xq);
  conv_mfma<<<256, 512, 0, stream>>>(xq, wq, out);
  norm_kernel<<<16 * 64, 256, 0, stream>>>(out, gamma);
}

// Round 4
// 139.393 us; speedup vs baseline: 11.0850x; 1.0260x over previous
//
#include <hip/hip_runtime.h>
#include <math.h>

// B=16, C_IN=256, C_OUT=256, H=W=64, K=3, NK=2
// weights: [2][256][256][3][3]; bank stride 589824 floats; per-o stride 2304.
//
// Pipeline:
//  1. scale_kernel: per (b,o) demod scale -> ws[scale]
//  2. wprep: combined+modulated+demod weights -> bf16 wq, LDS-image layout
//     per (b,ot4,c16): [p=20][ol=64][e=8], p = io*10 + j (j=9 zero dummy tap).
//  3. xprep: x -> bf16 xq [b][c16][rowp 66][colp 66][i 16], halo zeros baked.
//  4. conv_mfma: implicit GEMM via mfma_f32_16x16x32_bf16, double-buffered,
//     block = 256 thr (4 waves) = 64 o x 4 rows x 64 px, grid 1024 ->
//     2 blocks/CU (anti-phase barrier overlap). XCD-clustered by batch.
//  5. norm_kernel: channel RMSNorm * gamma * 16 + SiLU in place.

typedef __attribute__((ext_vector_type(8))) short short8;
typedef __attribute__((ext_vector_type(4))) float f32x4;

#define GLL16(src, dst)                                                       \
  __builtin_amdgcn_global_load_lds(                                           \
      (const __attribute__((address_space(1))) unsigned int*)(src),           \
      (__attribute__((address_space(3))) unsigned int*)(dst), 16, 0, 0)

static __device__ __forceinline__ unsigned short f2bf(float v) {
  union { float f; unsigned u; } u;
  u.f = v;
  unsigned r = u.u + 0x7FFF + ((u.u >> 16) & 1);  // RNE
  return (unsigned short)(r >> 16);
}

// ---------------------------------------------------------------------------
// Kernel 1: per-(b,o) demodulation scale
// ---------------------------------------------------------------------------
__global__ __launch_bounds__(256) void scale_kernel(
    const float* __restrict__ mod, const float* __restrict__ kmod,
    const float* __restrict__ weights, float* __restrict__ scale) {
  int bo = blockIdx.x;
  int b = bo >> 8, o = bo & 255;

  float k0 = kmod[b * 2 + 0], k1 = kmod[b * 2 + 1];
  float mx = fmaxf(k0, k1);
  float e0 = expf(k0 - mx), e1 = expf(k1 - mx);
  float ai = 1.0f / (e0 + e1);
  float a0 = e0 * ai, a1 = e1 * ai;

  int t = threadIdx.x;
  const float* w0 = weights + (size_t)o * 2304;
  const float* w1 = w0 + 589824;

  float s = 0.0f;
#pragma unroll
  for (int r = 0; r < 9; r++) {
    int idx = t + r * 256;
    int i = idx / 9;
    float wv = a0 * w0[idx] + a1 * w1[idx];
    wv *= (mod[b * 256 + i] + 1.0f);
    s += wv * wv;
  }
#pragma unroll
  for (int off = 32; off > 0; off >>= 1) s += __shfl_down(s, off);

  __shared__ float red[4];
  if ((t & 63) == 0) red[t >> 6] = s;
  __syncthreads();
  if (t == 0) {
    float tot = red[0] + red[1] + red[2] + red[3];
    scale[bo] = rsqrtf(fmaxf(tot, 1e-8f));
  }
}

// ---------------------------------------------------------------------------
// Kernel 2: weight prep -> bf16 LDS-image in wq.
// Grid 1024: blk = (b*4 + ot4)*16 + c. Chunk = [p20][ol64][e8] = 20 KB.
// ---------------------------------------------------------------------------
__global__ __launch_bounds__(256) void wprep(
    const float* __restrict__ mod, const float* __restrict__ kmod,
    const float* __restrict__ weights, const float* __restrict__ scale,
    unsigned short* __restrict__ wq) {
  __shared__ __align__(16) unsigned short buf[10240];
  int blk = blockIdx.x;  // (b*4 + ot)*16 + c
  int b = blk >> 6, ot = (blk >> 4) & 3, c = blk & 15;
  int t = threadIdx.x;

  float k0 = kmod[b * 2 + 0], k1 = kmod[b * 2 + 1];
  float mx = fmaxf(k0, k1);
  float e0 = expf(k0 - mx), e1 = expf(k1 - mx);
  float ai = 1.0f / (e0 + e1);
  float a0 = e0 * ai, a1 = e1 * ai;

  // zero the two dummy-tap rows (p=9, p=19): 1024 elems
#pragma unroll
  for (int k = 0; k < 4; ++k) {
    int e = t + k * 256;
    int half = e >> 9;
    buf[(half * 10 + 9) * 512 + (e & 511)] = 0;
  }

  int ol = t >> 2, q = t & 3;
  int o = ot * 64 + ol;
  float sc = scale[b * 256 + o];
#pragma unroll
  for (int io = 0; io < 2; ++io) {
#pragma unroll
    for (int e2 = 0; e2 < 2; ++e2) {
      int e = q * 2 + e2;
      int i = c * 16 + io * 8 + e;
      float f = (mod[b * 256 + i] + 1.0f) * sc;
      const float* w0 = &weights[((size_t)o * 256 + i) * 9];
      const float* w1 = w0 + 589824;
#pragma unroll
      for (int j = 0; j < 9; ++j) {
        float v = (a0 * w0[j] + a1 * w1[j]) * f;
        buf[(io * 10 + j) * 512 + ol * 8 + e] = f2bf(v);
      }
    }
  }
  __syncthreads();
  size_t base = (size_t)blk * 10240;
#pragma unroll
  for (int k = 0; k < 5; ++k) {
    int idx = t + k * 256;
    *(short8*)(wq + base + (size_t)idx * 8) = *(const short8*)&buf[idx * 8];
  }
}

// ---------------------------------------------------------------------------
// Kernel 3: x prep -> bf16 xq [b][c16][rowp 66][colp 66][i 16], halo zeroed.
// ---------------------------------------------------------------------------
__global__ __launch_bounds__(256) void xprep(
    const float* __restrict__ x, unsigned short* __restrict__ xq) {
  int blk = blockIdx.x;  // (b*16 + c)*66 + rowp
  int rowp = blk % 66;
  int bc = blk / 66;
  int b = bc >> 4, c = bc & 15;
  int t = threadIdx.x;
  size_t obase = (size_t)blk * 1056;

  if (rowp == 0 || rowp == 65) {
    for (int idx = t; idx < 1056; idx += 256) xq[obase + idx] = 0;
    return;
  }
  __shared__ __align__(16) unsigned short xs2[1056];
  int row = rowp - 1;
  for (int idx = t; idx < 1056; idx += 256) xs2[idx] = 0;
  __syncthreads();
#pragma unroll
  for (int k = 0; k < 4; ++k) {
    int idx = t + k * 256;  // 0..1023
    int il = idx >> 6, col = idx & 63;
    float v = x[(((size_t)b * 256 + c * 16 + il) * 64 + row) * 64 + col];
    xs2[(col + 1) * 16 + il] = f2bf(v);
  }
  __syncthreads();
  if (t < 132) *(short8*)(xq + obase + (size_t)t * 8) = *(const short8*)&xs2[t * 8];
}

// ---------------------------------------------------------------------------
// Kernel 4: implicit-GEMM conv, 2 blocks/CU, double-buffered.
// Grid 1024; block 256 thr (4 waves), wave = row. Tile 64 o x 4 rows x 64 px.
// ---------------------------------------------------------------------------
__global__ __launch_bounds__(256, 2) void conv_mfma(
    const unsigned short* __restrict__ xq, const unsigned short* __restrict__ wq,
    float* __restrict__ out) {
  __shared__ __align__(16) unsigned short wsm[2][10240];  // [p20][ol64][e8]
  __shared__ __align__(16) unsigned short xsm[2][9504];   // [rl6][colp66][i24]

  int bid = blockIdx.x;
  // XCD clustering: xcd = bid&7 owns b = {2*xcd, 2*xcd+1}
  int xcd = bid & 7;
  int kk = bid >> 3;  // 0..127
  int b = xcd * 2 + (kk >> 6);
  int rem = kk & 63;
  int ot = rem >> 4;  // 64-o quarter
  int rt = rem & 15;  // 4-row tile
  int r0 = rt * 4;

  int t = threadIdx.x;
  int w = t >> 6, lane = t & 63;
  int g = (t >> 4) & 3, lm = t & 15;

  // per-s LDS read offsets (bytes), loop-invariant across c
  int baddr_[5], aaddr_[5];
#pragma unroll
  for (int s = 0; s < 5; ++s) {
    int p = 4 * s + g;
    int io = (p >= 10) ? 1 : 0;
    int j = p - 10 * io;
    int jd3, jm3;
    if (j == 9) { jd3 = 0; jm3 = 0; }  // dummy tap: weights zero
    else { jd3 = (j >= 3) + (j >= 6); jm3 = j - 3 * jd3; }
    baddr_[s] = ((w + jd3) * 66 + lm + jm3) * 48 + io * 16;
    aaddr_[s] = p * 1024 + lm * 16;
  }

  // x-stage LDS offsets (elements): idx -> (rl, colp, eh)
  int xo0, xo1, xo2, xo3;
  {
    int idx, rl, rm;
    idx = t;        rl = idx / 132; rm = idx - rl * 132; xo0 = (rl * 66 + (rm >> 1)) * 24 + (rm & 1) * 8;
    idx = t + 256;  rl = idx / 132; rm = idx - rl * 132; xo1 = (rl * 66 + (rm >> 1)) * 24 + (rm & 1) * 8;
    idx = t + 512;  rl = idx / 132; rm = idx - rl * 132; xo2 = (rl * 66 + (rm >> 1)) * 24 + (rm & 1) * 8;
    idx = t + 768;  rl = idx / 132; rm = idx - rl * 132; xo3 = (rl * 66 + (rm >> 1)) * 24 + (rm & 1) * 8;
  }

  f32x4 acc[4][4];
#pragma unroll
  for (int mf = 0; mf < 4; ++mf)
#pragma unroll
    for (int nf = 0; nf < 4; ++nf) acc[mf][nf] = (f32x4){0.f, 0.f, 0.f, 0.f};

  short8 xr0, xr1, xr2, xr3;

#define XLOAD(cn)                                                              \
  {                                                                            \
    const unsigned short* xs_ =                                                \
        xq + (size_t)((b * 16 + (cn)) * 66 + r0) * 1056;                       \
    xr0 = *(const short8*)(xs_ + (size_t)t * 8);                               \
    xr1 = *(const short8*)(xs_ + (size_t)(t + 256) * 8);                       \
    xr2 = *(const short8*)(xs_ + (size_t)(t + 512) * 8);                       \
    if (t < 24) xr3 = *(const short8*)(xs_ + (size_t)(t + 768) * 8);           \
  }

#define WSTAGE(cn, nb)                                                         \
  {                                                                            \
    const unsigned short* ws_ =                                                \
        wq + ((size_t)(b * 4 + ot) * 16 + (cn)) * 10240 + w * 2560 + lane * 8; \
    unsigned short* wd_ = &wsm[nb][w * 2560];                                  \
    _Pragma("unroll")                                                          \
    for (int it = 0; it < 5; ++it) GLL16(ws_ + it * 512, wd_ + it * 512);      \
  }

#define XWRITE(nb)                                                             \
  {                                                                            \
    *(short8*)&xsm[nb][xo0] = xr0;                                             \
    *(short8*)&xsm[nb][xo1] = xr1;                                             \
    *(short8*)&xsm[nb][xo2] = xr2;                                             \
    if (t < 24) *(short8*)&xsm[nb][xo3] = xr3;                                 \
  }

  // prologue: stage c=0 into buffer 0
  XLOAD(0);
  WSTAGE(0, 0);
  XWRITE(0);
  __syncthreads();

  for (int c = 0; c < 16; ++c) {
    int cur = c & 1;
    if (c < 15) {
      XLOAD(c + 1);
      WSTAGE(c + 1, cur ^ 1);
    }
    // ---- compute on buffer cur ----
    {
      const char* wsb = (const char*)wsm[cur];
      const char* xsb = (const char*)xsm[cur];
#pragma unroll
      for (int s = 0; s < 5; ++s) {
        short8 A[4];
#pragma unroll
        for (int mf = 0; mf < 4; ++mf)
          A[mf] = *(const short8*)(wsb + aaddr_[s] + mf * 256);
#pragma unroll
        for (int nf = 0; nf < 4; ++nf) {
          short8 Bf = *(const short8*)(xsb + baddr_[s] + nf * 768);
#pragma unroll
          for (int mf = 0; mf < 4; ++mf)
            acc[mf][nf] =
                __builtin_amdgcn_mfma_f32_16x16x32_bf16(A[mf], Bf, acc[mf][nf], 0, 0, 0);
        }
      }
    }
    if (c < 15) XWRITE(cur ^ 1);
    __syncthreads();
  }

  // ---- epilogue: D col=lane&15 (px), row-in-frag=4*(lane>>4)+q (o) ----
  int row = r0 + w;
#pragma unroll
  for (int mf = 0; mf < 4; ++mf)
#pragma unroll
    for (int nf = 0; nf < 4; ++nf)
#pragma unroll
      for (int q = 0; q < 4; ++q) {
        int o = ot * 64 + mf * 16 + g * 4 + q;
        int col = nf * 16 + lm;
        out[(((size_t)b * 256 + o) * 64 + row) * 64 + col] = acc[mf][nf][q];
      }
#undef XLOAD
#undef WSTAGE
#undef XWRITE
}

// ---------------------------------------------------------------------------
// Kernel 5: channel RMSNorm * gamma * 16 + SiLU, in place.
// ---------------------------------------------------------------------------
__global__ __launch_bounds__(256) void norm_kernel(
    float* __restrict__ y, const float* __restrict__ gamma) {
  int blk = blockIdx.x;
  int b = blk >> 6, h = blk & 63;
  int t = threadIdx.x;
  int p = t & 63, og = t >> 6;

  size_t base = (((size_t)b * 256) * 64 + h) * 64 + p;
  float yv[64];
  float s = 0.0f;
#pragma unroll
  for (int k = 0; k < 64; k++) {
    yv[k] = y[base + (size_t)(og * 64 + k) * 4096];
    s = fmaf(yv[k], yv[k], s);
  }

  __shared__ float red[4][64];
  __shared__ float invs[64];
  red[og][p] = s;
  __syncthreads();
  if (og == 0) {
    float tot = red[0][p] + red[1][p] + red[2][p] + red[3][p];
    float nrm = sqrtf(tot);
    invs[p] = 16.0f / fmaxf(nrm, 1e-12f);
  }
  __syncthreads();
  float iv = invs[p];
#pragma unroll
  for (int k = 0; k < 64; k++) {
    int o = og * 64 + k;
    float v = yv[k] * iv * gamma[o];
    float sg = 1.0f / (1.0f + expf(-v));
    y[base + (size_t)o * 4096] = v * sg;
  }
}

extern "C" void kernel_launch(void* const* d_in, const int* in_sizes, int n_in,
                              void* d_out, int out_size, void* d_ws, size_t ws_size,
                              hipStream_t stream) {
  const float* x = (const float*)d_in[0];
  const float* mod = (const float*)d_in[1];
  const float* kmod = (const float*)d_in[2];
  const float* weights = (const float*)d_in[3];
  const float* gamma = (const float*)d_in[4];
  float* out = (float*)d_out;

  // ws layout: wq 20,971,520 B | scale 16,384 B | xq 35,684,352 B  (~56.7 MB)
  unsigned short* wq = (unsigned short*)d_ws;
  float* scale = (float*)((char*)d_ws + 20971520);
  unsigned short* xq = (unsigned short*)((char*)d_ws + 20987904);

  scale_kernel<<<16 * 256, 256, 0, stream>>>(mod, kmod, weights, scale);
  wprep<<<1024, 256, 0, stream>>>(mod, kmod, weights, scale, wq);
  xprep<<<16 * 16 * 66, 256, 0, stream>>>(x, xq);
  conv_mfma<<<1024, 256, 0, stream>>>(xq, wq, out);
  norm_kernel<<<16 * 64, 256, 0, stream>>>(out, gamma);
}